// Round 6
// baseline (532.240 us; speedup 1.0000x reference)
//
#include <hip/hip_runtime.h>
#include <hip/hip_bf16.h>

#define NEDGES 80000
#define NTRIP  640000
#define NQUAD  1280000

typedef __attribute__((ext_vector_type(8))) short short8;
typedef __attribute__((ext_vector_type(4))) float f32x4;

__device__ __forceinline__ unsigned short f2bf(float f) {
  __hip_bfloat16 h = __float2bfloat16(f);
  return reinterpret_cast<unsigned short&>(h);
}
__device__ __forceinline__ float bf2f(short s) {
  union { unsigned u; float f; } u;
  u.u = ((unsigned)(unsigned short)s) << 16;
  return u.f;
}
__device__ __forceinline__ float sSiLU(float x) {
  return x * (1.0f / 0.6f) / (1.0f + __expf(-x));
}

// ---------------- pack kernel: weights -> bf16, MFMA B-fragment order ----------
__device__ __forceinline__ void pack_one(const float* __restrict__ W,
                                         unsigned short* __restrict__ dst,
                                         int p, int NT, int Ksrc, int N) {
  int j = p & 7;
  int l = (p >> 3) & 63;
  int rest = p >> 9;
  int nt = rest % NT;
  int kb = rest / NT;
  int k = kb * 32 + ((l >> 4) << 3) + j;
  int n = nt * 16 + (l & 15);
  float v = (k < Ksrc) ? W[(size_t)k * N + n] : 0.0f;
  dst[p] = f2bf(v);
}

__global__ __launch_bounds__(256) void kpack(
    const float* __restrict__ Wd, const float* __restrict__ Wrbf,
    const float* __restrict__ Wdown, const float* __restrict__ Wbil,
    const float* __restrict__ Wupca, const float* __restrict__ Wupac,
    unsigned short* __restrict__ WdP, unsigned short* __restrict__ WrbfP,
    unsigned short* __restrict__ WdownP, unsigned short* __restrict__ WbilP,
    unsigned short* __restrict__ WupcaP, unsigned short* __restrict__ WupacP) {
  int idx = blockIdx.x * 256 + threadIdx.x;
  if (idx < 16384)        pack_one(Wd,    WdP,    idx,          8, 128,  128);
  else if (idx < 20480)   pack_one(Wrbf,  WrbfP,  idx - 16384,  8, 16,   128);
  else if (idx < 28672)   pack_one(Wdown, WdownP, idx - 20480,  4, 128,  64);
  else if (idx < 159744)  pack_one(Wbil,  WbilP,  idx - 28672,  4, 2048, 64);
  else if (idx < 167936)  pack_one(Wupca, WupcaP, idx - 159744, 8, 64,   128);
  else if (idx < 176128)  pack_one(Wupac, WupacP, idx - 167936, 8, 64,   128);
}

// ---------------- kernel A: x_down(bf16) = ss( (ss(m@Wd)*(rbf@Wrbf)) @ Wdown ) --
__global__ __launch_bounds__(256) void kA(
    const float* __restrict__ m, const float* __restrict__ rbf,
    const unsigned short* __restrict__ WdP, const unsigned short* __restrict__ WrbfP,
    const unsigned short* __restrict__ WdownP, unsigned short* __restrict__ x_down) {
  __shared__ unsigned short h_lds[4][16][136];
  const int tid = threadIdx.x;
  const int w = tid >> 6, l = tid & 63;
  const int el = l & 15, g = l >> 4;
  const int ebase = blockIdx.x * 64 + w * 16;

  short8 am[4];
  {
    const float* mrow = m + (size_t)(ebase + el) * 128 + g * 8;
#pragma unroll
    for (int kb = 0; kb < 4; ++kb) {
      const f32x4 lo = *reinterpret_cast<const f32x4*>(mrow + kb * 32);
      const f32x4 hi = *reinterpret_cast<const f32x4*>(mrow + kb * 32 + 4);
      short8 a;
      a[0] = f2bf(lo[0]); a[1] = f2bf(lo[1]); a[2] = f2bf(lo[2]); a[3] = f2bf(lo[3]);
      a[4] = f2bf(hi[0]); a[5] = f2bf(hi[1]); a[6] = f2bf(hi[2]); a[7] = f2bf(hi[3]);
      am[kb] = a;
    }
  }
  short8 ar;
  {
    const float* rrow = rbf + (size_t)(ebase + el) * 16 + (g & 1) * 8;
    const f32x4 lo = *reinterpret_cast<const f32x4*>(rrow);
    const f32x4 hi = *reinterpret_cast<const f32x4*>(rrow + 4);
    ar[0] = f2bf(lo[0]); ar[1] = f2bf(lo[1]); ar[2] = f2bf(lo[2]); ar[3] = f2bf(lo[3]);
    ar[4] = f2bf(hi[0]); ar[5] = f2bf(hi[1]); ar[6] = f2bf(hi[2]); ar[7] = f2bf(hi[3]);
  }

  f32x4 acc1[8], acc2[8];
  const f32x4 z = {0.f, 0.f, 0.f, 0.f};
#pragma unroll
  for (int nt = 0; nt < 8; ++nt) { acc1[nt] = z; acc2[nt] = z; }

#pragma unroll
  for (int kb = 0; kb < 4; ++kb) {
#pragma unroll
    for (int nt = 0; nt < 8; ++nt) {
      short8 b = *reinterpret_cast<const short8*>(WdP + (((kb * 8 + nt) * 64 + l) << 3));
      acc1[nt] = __builtin_amdgcn_mfma_f32_16x16x32_bf16(am[kb], b, acc1[nt], 0, 0, 0);
    }
  }
#pragma unroll
  for (int nt = 0; nt < 8; ++nt) {
    short8 b = *reinterpret_cast<const short8*>(WrbfP + ((nt * 64 + l) << 3));
    acc2[nt] = __builtin_amdgcn_mfma_f32_16x16x32_bf16(ar, b, acc2[nt], 0, 0, 0);
  }

#pragma unroll
  for (int nt = 0; nt < 8; ++nt)
#pragma unroll
    for (int r = 0; r < 4; ++r) {
      float h = sSiLU(acc1[nt][r]) * acc2[nt][r];
      h_lds[w][g * 4 + r][nt * 16 + el] = f2bf(h);
    }
  __syncthreads();

  f32x4 acc3[4];
#pragma unroll
  for (int nt = 0; nt < 4; ++nt) acc3[nt] = z;
#pragma unroll
  for (int kb = 0; kb < 4; ++kb) {
    short8 a = *reinterpret_cast<const short8*>(&h_lds[w][el][kb * 32 + g * 8]);
#pragma unroll
    for (int nt = 0; nt < 4; ++nt) {
      short8 b = *reinterpret_cast<const short8*>(WdownP + (((kb * 4 + nt) * 64 + l) << 3));
      acc3[nt] = __builtin_amdgcn_mfma_f32_16x16x32_bf16(a, b, acc3[nt], 0, 0, 0);
    }
  }
#pragma unroll
  for (int nt = 0; nt < 4; ++nt)
#pragma unroll
    for (int r = 0; r < 4; ++r)
      x_down[(size_t)(ebase + g * 4 + r) * 64 + nt * 16 + el] = f2bf(sSiLU(acc3[nt][r]));
}

// ---------------- kernel S: sumk[e][c][s] = sum_k sph[e][k][s] * row(e,k,c) -----
// row(e,k,c) = x_down[intm[abd[q]]][c] * (cbf[abd[q]] @ Wcbf)[c],  q = k*NE + e.
// Hybrid structure (round-4 layout + pipelining):
//  - indices (abd/intm) stay SCALAR -> SGPRs, zero VGPR cost, x_down rows as
//    sgpr-base + lane-offset coalesced 128B line gathers
//  - cbf DATA on the VECTOR path: one global_load_dwordx4 per edge covers all
//    16 quad rows (lane l -> quad l>>2, floats (l&3)*4), staged via 4KB
//    wave-private LDS (write at iter top, reload during compute), read back
//    as uniform broadcast (conflict-free)
//  - 4 edges per wave, 2-ahead scalar / 1-ahead vector pipeline
//  - XCD-contiguous edge chunks (5000 blocks = 8 x 625) to de-duplicate
//    abd/intm/sph line fetches across XCD L2s
__global__ __launch_bounds__(256) void kS(
    const float* __restrict__ cbf, const float* __restrict__ sph,
    const int* __restrict__ abd, const int* __restrict__ intm,
    const unsigned short* __restrict__ x_down, const float* __restrict__ Wcbf,
    unsigned short* __restrict__ sumk) {
  __shared__ float cbf_lds[4][16][16];   // 4KB, wave-private slices
  const int tid = threadIdx.x;
  const int w = tid >> 6, c = tid & 63;
  const int b = blockIdx.x;
  const int chunk = (b & 7) * 625 + (b >> 3);   // bijective, XCD-contiguous
  const int e0 = chunk * 16 + w * 4;            // 4 edges per wave

  float wc[16];
#pragma unroll
  for (int r = 0; r < 16; ++r) wc[r] = Wcbf[r * 64 + c];

  // ---- prologue: edge e0 chain + te(e0+1) + cq(e0) ----
  int teN[16];
  int es[16];
  {
    int teC[16];
#pragma unroll
    for (int k = 0; k < 16; ++k)
      teC[k] = __builtin_amdgcn_readfirstlane(abd[(size_t)k * NEDGES + e0]);
#pragma unroll
    for (int k = 0; k < 16; ++k)
      es[k] = __builtin_amdgcn_readfirstlane(intm[teC[k]]);
  }
  unsigned short xr[16];
#pragma unroll
  for (int k = 0; k < 16; ++k) xr[k] = x_down[(size_t)es[k] * 64 + c];
#pragma unroll
  for (int k = 0; k < 16; ++k)
    teN[k] = __builtin_amdgcn_readfirstlane(abd[(size_t)k * NEDGES + (e0 + 1)]);
  f32x4 cq;
  {
    const int tq = abd[(size_t)(c >> 2) * NEDGES + e0];   // per-lane vector load
    cq = *reinterpret_cast<const f32x4*>(cbf + (size_t)tq * 16 + (c & 3) * 4);
  }

#pragma unroll
  for (int ee = 0; ee < 4; ++ee) {
    const int e   = e0 + ee;
    const int en1 = (ee < 3) ? e + 1 : e;        // clamped prefetch targets
    const int en2 = (ee < 2) ? e + 2 : e0 + 3;

    // park this edge's cbf tile (regs -> wave-private LDS)
    *reinterpret_cast<f32x4*>(&cbf_lds[w][c >> 2][(c & 3) * 4]) = cq;

    // issue next-edge loads (overlap with this edge's FMA block):
    int esN[16];
#pragma unroll
    for (int k = 0; k < 16; ++k)
      esN[k] = __builtin_amdgcn_readfirstlane(intm[teN[k]]);   // intm(e+1)
    int teNN[16];
#pragma unroll
    for (int k = 0; k < 16; ++k)
      teNN[k] = __builtin_amdgcn_readfirstlane(abd[(size_t)k * NEDGES + en2]); // te(e+2)
    {
      const int tq = abd[(size_t)(c >> 2) * NEDGES + en1];
      cq = *reinterpret_cast<const f32x4*>(cbf + (size_t)tq * 16 + (c & 3) * 4); // cq(e+1)
    }

    // ---- compute edge e ----
    const float* spe = sph + (size_t)e * 168;
    float sk[7] = {0.f, 0.f, 0.f, 0.f, 0.f, 0.f, 0.f};
#pragma unroll
    for (int k = 0; k < 16; ++k) {
      const f32x4* cr = reinterpret_cast<const f32x4*>(&cbf_lds[w][k][0]);
      const f32x4 q0 = cr[0], q1 = cr[1], q2 = cr[2], q3 = cr[3];  // broadcast
      float proj = 0.f;
#pragma unroll
      for (int r = 0; r < 4; ++r) {
        proj = fmaf(q0[r], wc[r], proj);
        proj = fmaf(q1[r], wc[4 + r], proj);
        proj = fmaf(q2[r], wc[8 + r], proj);
        proj = fmaf(q3[r], wc[12 + r], proj);
      }
      const float row = bf2f((short)xr[k]) * proj;
#pragma unroll
      for (int s = 0; s < 7; ++s) sk[s] = fmaf(spe[k * 7 + s], row, sk[s]);
    }
    short8 sv;
#pragma unroll
    for (int s = 0; s < 7; ++s) sv[s] = (short)f2bf(sk[s]);
    sv[7] = 0;
    *reinterpret_cast<short8*>(sumk + (size_t)e * 512 + c * 8) = sv;

    // rotate pipeline state: xr(e+1) gathers + te shift
#pragma unroll
    for (int k = 0; k < 16; ++k) xr[k] = x_down[(size_t)esN[k] * 64 + c];
#pragma unroll
    for (int k = 0; k < 16; ++k) teN[k] = teNN[k];
  }
}

// ---------------- kernel B2 (dense): sumk -> t -> bilinear MFMA -> up-proj -----
__global__ __launch_bounds__(256) void kB2(
    const float* __restrict__ sbfW1, const unsigned short* __restrict__ sumk,
    const unsigned short* __restrict__ WbilP, const unsigned short* __restrict__ WupcaP,
    const unsigned short* __restrict__ WupacP, float* __restrict__ out) {
  __shared__ unsigned short sk_lds[4][16][520];
  __shared__ unsigned short x_lds[4][16][72];
  const int tid = threadIdx.x;
  const int w = tid >> 6, l = tid & 63;
  const int el = l & 15, g = l >> 4;
  const int ebase = blockIdx.x * 64 + w * 16;

#pragma unroll
  for (int i = 0; i < 16; ++i) {
    const short8 v = *reinterpret_cast<const short8*>(sumk + (size_t)(ebase + i) * 512 + l * 8);
    *reinterpret_cast<short8*>(&sk_lds[w][i][l * 8]) = v;
  }

  float w1r[56];
  {
    const f32x4* wp = reinterpret_cast<const f32x4*>(sbfW1 + (size_t)(ebase + el) * 224 + g * 56);
#pragma unroll
    for (int qq = 0; qq < 14; ++qq) {
      f32x4 v = wp[qq];
      w1r[qq * 4 + 0] = v[0]; w1r[qq * 4 + 1] = v[1];
      w1r[qq * 4 + 2] = v[2]; w1r[qq * 4 + 3] = v[3];
    }
  }
  __syncthreads();

  const f32x4 z = {0.f, 0.f, 0.f, 0.f};
  f32x4 acc[4];
#pragma unroll
  for (int nt = 0; nt < 4; ++nt) acc[nt] = z;

#pragma unroll 4
  for (int kb = 0; kb < 64; ++kb) {
    const short8 skv = *reinterpret_cast<const short8*>(&sk_lds[w][el][kb * 8]);
    float skf[7];
#pragma unroll
    for (int s = 0; s < 7; ++s) skf[s] = bf2f(skv[s]);
    short8 a;
#pragma unroll
    for (int j = 0; j < 8; ++j) {
      float t = 0.f;
#pragma unroll
      for (int s = 0; s < 7; ++s) t = fmaf(w1r[j * 7 + s], skf[s], t);
      a[j] = (short)f2bf(t);
    }
    const unsigned short* bp = WbilP + (((kb * 4) * 64 + l) << 3);
#pragma unroll
    for (int nt = 0; nt < 4; ++nt) {
      short8 b = *reinterpret_cast<const short8*>(bp + ((nt * 64) << 3));
      acc[nt] = __builtin_amdgcn_mfma_f32_16x16x32_bf16(a, b, acc[nt], 0, 0, 0);
    }
  }

#pragma unroll
  for (int nt = 0; nt < 4; ++nt)
#pragma unroll
    for (int r = 0; r < 4; ++r)
      x_lds[w][g * 4 + r][nt * 16 + el] = f2bf(acc[nt][r]);
  __syncthreads();

  f32x4 aca[8], acb[8];
#pragma unroll
  for (int nt = 0; nt < 8; ++nt) { aca[nt] = z; acb[nt] = z; }
#pragma unroll
  for (int kb = 0; kb < 2; ++kb) {
    short8 a = *reinterpret_cast<const short8*>(&x_lds[w][el][kb * 32 + g * 8]);
#pragma unroll
    for (int nt = 0; nt < 8; ++nt) {
      short8 b1 = *reinterpret_cast<const short8*>(WupcaP + (((kb * 8 + nt) * 64 + l) << 3));
      short8 b2 = *reinterpret_cast<const short8*>(WupacP + (((kb * 8 + nt) * 64 + l) << 3));
      aca[nt] = __builtin_amdgcn_mfma_f32_16x16x32_bf16(a, b1, aca[nt], 0, 0, 0);
      acb[nt] = __builtin_amdgcn_mfma_f32_16x16x32_bf16(a, b2, acb[nt], 0, 0, 0);
    }
  }
  const float inv = 0.70710678118654752f;
#pragma unroll
  for (int nt = 0; nt < 8; ++nt)
#pragma unroll
    for (int r = 0; r < 4; ++r) {
      float v = (sSiLU(aca[nt][r]) + sSiLU(acb[nt][r ^ 1])) * inv;
      out[(size_t)(ebase + g * 4 + r) * 128 + nt * 16 + el] = v;
    }
}

// ---------------- kernel B (fallback, round-2 structure; bf16 x_down) ----------
__global__ __launch_bounds__(256) void kBfb(
    const float* __restrict__ cbf, const float* __restrict__ sbfW1,
    const float* __restrict__ sph, const int* __restrict__ abd,
    const int* __restrict__ intm, const unsigned short* __restrict__ x_down,
    const unsigned short* __restrict__ WbilP, const unsigned short* __restrict__ WupcaP,
    const unsigned short* __restrict__ WupacP, const float* __restrict__ Wcbf,
    float* __restrict__ out) {
  __shared__ unsigned short sumk[4][16][520];
  __shared__ unsigned short x_lds[4][16][72];
  const int tid = threadIdx.x;
  const int w = tid >> 6, l = tid & 63;
  const int el = l & 15, g = l >> 4;
  const int ebase = blockIdx.x * 64 + w * 16;
  const int c = l;

  float wc[16];
#pragma unroll
  for (int r = 0; r < 16; ++r) wc[r] = Wcbf[r * 64 + c];

  int te[16], es[16];
#pragma unroll
  for (int k = 0; k < 16; ++k)
    te[k] = __builtin_amdgcn_readfirstlane(abd[k * NEDGES + ebase]);
#pragma unroll
  for (int k = 0; k < 16; ++k)
    es[k] = __builtin_amdgcn_readfirstlane(intm[te[k]]);

  for (int ee = 0; ee < 16; ++ee) {
    const int e = ebase + ee;
    const int en = (ee < 15) ? (e + 1) : e;
    int te2[16], es2[16];
#pragma unroll
    for (int k = 0; k < 16; ++k)
      te2[k] = __builtin_amdgcn_readfirstlane(abd[k * NEDGES + en]);
    float xr[16];
#pragma unroll
    for (int k = 0; k < 16; ++k)
      xr[k] = bf2f((short)x_down[(size_t)es[k] * 64 + c]);
#pragma unroll
    for (int k = 0; k < 16; ++k)
      es2[k] = __builtin_amdgcn_readfirstlane(intm[te2[k]]);

    const float* spe = sph + (size_t)e * 168;
    float sk[7] = {0.f, 0.f, 0.f, 0.f, 0.f, 0.f, 0.f};
#pragma unroll
    for (int k = 0; k < 16; ++k) {
      const f32x4* cp = reinterpret_cast<const f32x4*>(cbf + (size_t)te[k] * 16);
      const f32x4 c0 = cp[0], c1 = cp[1], c2 = cp[2], c3 = cp[3];
      float proj = 0.f;
#pragma unroll
      for (int r = 0; r < 4; ++r) {
        proj = fmaf(c0[r], wc[r], proj);
        proj = fmaf(c1[r], wc[4 + r], proj);
        proj = fmaf(c2[r], wc[8 + r], proj);
        proj = fmaf(c3[r], wc[12 + r], proj);
      }
      const float row = xr[k] * proj;
#pragma unroll
      for (int s = 0; s < 7; ++s) sk[s] = fmaf(spe[k * 7 + s], row, sk[s]);
    }
    short8 sv;
#pragma unroll
    for (int s = 0; s < 7; ++s) sv[s] = (short)f2bf(sk[s]);
    sv[7] = 0;
    *reinterpret_cast<short8*>(&sumk[w][ee][c * 8]) = sv;
#pragma unroll
    for (int k = 0; k < 16; ++k) { te[k] = te2[k]; es[k] = es2[k]; }
  }
  __syncthreads();

  float w1r[56];
  {
    const f32x4* wp = reinterpret_cast<const f32x4*>(sbfW1 + (size_t)(ebase + el) * 224 + g * 56);
#pragma unroll
    for (int qq = 0; qq < 14; ++qq) {
      f32x4 v = wp[qq];
      w1r[qq * 4 + 0] = v[0]; w1r[qq * 4 + 1] = v[1];
      w1r[qq * 4 + 2] = v[2]; w1r[qq * 4 + 3] = v[3];
    }
  }
  const f32x4 z = {0.f, 0.f, 0.f, 0.f};
  f32x4 acc[4];
#pragma unroll
  for (int nt = 0; nt < 4; ++nt) acc[nt] = z;
#pragma unroll 4
  for (int kb = 0; kb < 64; ++kb) {
    const short8 skv = *reinterpret_cast<const short8*>(&sumk[w][el][kb * 8]);
    float skf[7];
#pragma unroll
    for (int s = 0; s < 7; ++s) skf[s] = bf2f(skv[s]);
    short8 a;
#pragma unroll
    for (int j = 0; j < 8; ++j) {
      float t = 0.f;
#pragma unroll
      for (int s = 0; s < 7; ++s) t = fmaf(w1r[j * 7 + s], skf[s], t);
      a[j] = (short)f2bf(t);
    }
    const unsigned short* bp = WbilP + (((kb * 4) * 64 + l) << 3);
#pragma unroll
    for (int nt = 0; nt < 4; ++nt) {
      short8 b = *reinterpret_cast<const short8*>(bp + ((nt * 64) << 3));
      acc[nt] = __builtin_amdgcn_mfma_f32_16x16x32_bf16(a, b, acc[nt], 0, 0, 0);
    }
  }
#pragma unroll
  for (int nt = 0; nt < 4; ++nt)
#pragma unroll
    for (int r = 0; r < 4; ++r)
      x_lds[w][g * 4 + r][nt * 16 + el] = f2bf(acc[nt][r]);
  __syncthreads();

  f32x4 aca[8], acb[8];
#pragma unroll
  for (int nt = 0; nt < 8; ++nt) { aca[nt] = z; acb[nt] = z; }
#pragma unroll
  for (int kb = 0; kb < 2; ++kb) {
    short8 a = *reinterpret_cast<const short8*>(&x_lds[w][el][kb * 32 + g * 8]);
#pragma unroll
    for (int nt = 0; nt < 8; ++nt) {
      short8 b1 = *reinterpret_cast<const short8*>(WupcaP + (((kb * 8 + nt) * 64 + l) << 3));
      short8 b2 = *reinterpret_cast<const short8*>(WupacP + (((kb * 8 + nt) * 64 + l) << 3));
      aca[nt] = __builtin_amdgcn_mfma_f32_16x16x32_bf16(a, b1, aca[nt], 0, 0, 0);
      acb[nt] = __builtin_amdgcn_mfma_f32_16x16x32_bf16(a, b2, acb[nt], 0, 0, 0);
    }
  }
  const float inv = 0.70710678118654752f;
#pragma unroll
  for (int nt = 0; nt < 8; ++nt)
#pragma unroll
    for (int r = 0; r < 4; ++r) {
      float v = (sSiLU(aca[nt][r]) + sSiLU(acb[nt][r ^ 1])) * inv;
      out[(size_t)(ebase + g * 4 + r) * 128 + nt * 16 + el] = v;
    }
}

// ---------------- launch ----------------
extern "C" void kernel_launch(void* const* d_in, const int* in_sizes, int n_in,
                              void* d_out, int out_size, void* d_ws, size_t ws_size,
                              hipStream_t stream) {
  const float* m     = (const float*)d_in[0];
  const float* rbf   = (const float*)d_in[1];
  const float* cbf   = (const float*)d_in[2];
  const float* sbfW1 = (const float*)d_in[3];
  const float* sph   = (const float*)d_in[4];
  const int* intm = (const int*)d_in[8];
  const int* abd  = (const int*)d_in[9];
  const float* Wd    = (const float*)d_in[10];
  const float* Wrbf  = (const float*)d_in[11];
  const float* Wcbf  = (const float*)d_in[12];
  const float* Wdown = (const float*)d_in[13];
  const float* Wbil  = (const float*)d_in[14];
  const float* Wupca = (const float*)d_in[15];
  const float* Wupac = (const float*)d_in[16];

  char* ws = (char*)d_ws;
  unsigned short* WdP    = (unsigned short*)(ws + 0);
  unsigned short* WrbfP  = (unsigned short*)(ws + 32768);
  unsigned short* WdownP = (unsigned short*)(ws + 40960);
  unsigned short* WbilP  = (unsigned short*)(ws + 57344);
  unsigned short* WupcaP = (unsigned short*)(ws + 319488);
  unsigned short* WupacP = (unsigned short*)(ws + 335872);
  unsigned short* x_down = (unsigned short*)(ws + 352256);            // 10,240,000 B
  unsigned short* sumk   = (unsigned short*)(ws + 352256 + 10240000); // 81,920,000 B
  const size_t needed = 352256ull + 10240000ull + 81920000ull;

  kpack<<<688, 256, 0, stream>>>(Wd, Wrbf, Wdown, Wbil, Wupca, Wupac,
                                 WdP, WrbfP, WdownP, WbilP, WupcaP, WupacP);
  kA<<<1250, 256, 0, stream>>>(m, rbf, WdP, WrbfP, WdownP, x_down);
  if (ws_size >= needed) {
    kS<<<5000, 256, 0, stream>>>(cbf, sph, abd, intm, x_down, Wcbf, sumk);
    kB2<<<1250, 256, 0, stream>>>(sbfW1, sumk, WbilP, WupcaP, WupacP, (float*)d_out);
  } else {
    kBfb<<<1250, 256, 0, stream>>>(cbf, sbfW1, sph, abd, intm, x_down,
                                   WbilP, WupcaP, WupacP, Wcbf, (float*)d_out);
  }
}

// Round 7
// 307.676 us; speedup vs baseline: 1.7299x; 1.7299x over previous
//
#include <hip/hip_runtime.h>
#include <hip/hip_bf16.h>

#define NEDGES 80000
#define NTRIP  640000
#define NQUAD  1280000

typedef __attribute__((ext_vector_type(8))) short short8;
typedef __attribute__((ext_vector_type(4))) float f32x4;

__device__ __forceinline__ unsigned short f2bf(float f) {
  __hip_bfloat16 h = __float2bfloat16(f);
  return reinterpret_cast<unsigned short&>(h);
}
__device__ __forceinline__ float bf2f(short s) {
  union { unsigned u; float f; } u;
  u.u = ((unsigned)(unsigned short)s) << 16;
  return u.f;
}
__device__ __forceinline__ float sSiLU(float x) {
  return x * (1.0f / 0.6f) / (1.0f + __expf(-x));
}

// ---------------- pack kernel: weights -> bf16, MFMA B-fragment order ----------
__device__ __forceinline__ void pack_one(const float* __restrict__ W,
                                         unsigned short* __restrict__ dst,
                                         int p, int NT, int Ksrc, int N) {
  int j = p & 7;
  int l = (p >> 3) & 63;
  int rest = p >> 9;
  int nt = rest % NT;
  int kb = rest / NT;
  int k = kb * 32 + ((l >> 4) << 3) + j;
  int n = nt * 16 + (l & 15);
  float v = (k < Ksrc) ? W[(size_t)k * N + n] : 0.0f;
  dst[p] = f2bf(v);
}

__global__ __launch_bounds__(256) void kpack(
    const float* __restrict__ Wd, const float* __restrict__ Wrbf,
    const float* __restrict__ Wdown, const float* __restrict__ Wbil,
    const float* __restrict__ Wupca, const float* __restrict__ Wupac,
    unsigned short* __restrict__ WdP, unsigned short* __restrict__ WrbfP,
    unsigned short* __restrict__ WdownP, unsigned short* __restrict__ WbilP,
    unsigned short* __restrict__ WupcaP, unsigned short* __restrict__ WupacP) {
  int idx = blockIdx.x * 256 + threadIdx.x;
  if (idx < 16384)        pack_one(Wd,    WdP,    idx,          8, 128,  128);
  else if (idx < 20480)   pack_one(Wrbf,  WrbfP,  idx - 16384,  8, 16,   128);
  else if (idx < 28672)   pack_one(Wdown, WdownP, idx - 20480,  4, 128,  64);
  else if (idx < 159744)  pack_one(Wbil,  WbilP,  idx - 28672,  4, 2048, 64);
  else if (idx < 167936)  pack_one(Wupca, WupcaP, idx - 159744, 8, 64,   128);
  else if (idx < 176128)  pack_one(Wupac, WupacP, idx - 167936, 8, 64,   128);
}

// ---------------- kernel A: x_down(bf16) = ss( (ss(m@Wd)*(rbf@Wrbf)) @ Wdown ) --
__global__ __launch_bounds__(256) void kA(
    const float* __restrict__ m, const float* __restrict__ rbf,
    const unsigned short* __restrict__ WdP, const unsigned short* __restrict__ WrbfP,
    const unsigned short* __restrict__ WdownP, unsigned short* __restrict__ x_down) {
  __shared__ unsigned short h_lds[4][16][136];
  const int tid = threadIdx.x;
  const int w = tid >> 6, l = tid & 63;
  const int el = l & 15, g = l >> 4;
  const int ebase = blockIdx.x * 64 + w * 16;

  short8 am[4];
  {
    const float* mrow = m + (size_t)(ebase + el) * 128 + g * 8;
#pragma unroll
    for (int kb = 0; kb < 4; ++kb) {
      const f32x4 lo = *reinterpret_cast<const f32x4*>(mrow + kb * 32);
      const f32x4 hi = *reinterpret_cast<const f32x4*>(mrow + kb * 32 + 4);
      short8 a;
      a[0] = f2bf(lo[0]); a[1] = f2bf(lo[1]); a[2] = f2bf(lo[2]); a[3] = f2bf(lo[3]);
      a[4] = f2bf(hi[0]); a[5] = f2bf(hi[1]); a[6] = f2bf(hi[2]); a[7] = f2bf(hi[3]);
      am[kb] = a;
    }
  }
  short8 ar;
  {
    const float* rrow = rbf + (size_t)(ebase + el) * 16 + (g & 1) * 8;
    const f32x4 lo = *reinterpret_cast<const f32x4*>(rrow);
    const f32x4 hi = *reinterpret_cast<const f32x4*>(rrow + 4);
    ar[0] = f2bf(lo[0]); ar[1] = f2bf(lo[1]); ar[2] = f2bf(lo[2]); ar[3] = f2bf(lo[3]);
    ar[4] = f2bf(hi[0]); ar[5] = f2bf(hi[1]); ar[6] = f2bf(hi[2]); ar[7] = f2bf(hi[3]);
  }

  f32x4 acc1[8], acc2[8];
  const f32x4 z = {0.f, 0.f, 0.f, 0.f};
#pragma unroll
  for (int nt = 0; nt < 8; ++nt) { acc1[nt] = z; acc2[nt] = z; }

#pragma unroll
  for (int kb = 0; kb < 4; ++kb) {
#pragma unroll
    for (int nt = 0; nt < 8; ++nt) {
      short8 b = *reinterpret_cast<const short8*>(WdP + (((kb * 8 + nt) * 64 + l) << 3));
      acc1[nt] = __builtin_amdgcn_mfma_f32_16x16x32_bf16(am[kb], b, acc1[nt], 0, 0, 0);
    }
  }
#pragma unroll
  for (int nt = 0; nt < 8; ++nt) {
    short8 b = *reinterpret_cast<const short8*>(WrbfP + ((nt * 64 + l) << 3));
    acc2[nt] = __builtin_amdgcn_mfma_f32_16x16x32_bf16(ar, b, acc2[nt], 0, 0, 0);
  }

#pragma unroll
  for (int nt = 0; nt < 8; ++nt)
#pragma unroll
    for (int r = 0; r < 4; ++r) {
      float h = sSiLU(acc1[nt][r]) * acc2[nt][r];
      h_lds[w][g * 4 + r][nt * 16 + el] = f2bf(h);
    }
  __syncthreads();

  f32x4 acc3[4];
#pragma unroll
  for (int nt = 0; nt < 4; ++nt) acc3[nt] = z;
#pragma unroll
  for (int kb = 0; kb < 4; ++kb) {
    short8 a = *reinterpret_cast<const short8*>(&h_lds[w][el][kb * 32 + g * 8]);
#pragma unroll
    for (int nt = 0; nt < 4; ++nt) {
      short8 b = *reinterpret_cast<const short8*>(WdownP + (((kb * 4 + nt) * 64 + l) << 3));
      acc3[nt] = __builtin_amdgcn_mfma_f32_16x16x32_bf16(a, b, acc3[nt], 0, 0, 0);
    }
  }
#pragma unroll
  for (int nt = 0; nt < 4; ++nt)
#pragma unroll
    for (int r = 0; r < 4; ++r)
      x_down[(size_t)(ebase + g * 4 + r) * 64 + nt * 16 + el] = f2bf(sSiLU(acc3[nt][r]));
}

// ---------------- kernel S: sumk[e][c][s] = sum_k sph[e][k][s] * row(e,k,c) -----
// row(e,k,c) = x_down[intm[abd[q]]][c] * (cbf[abd[q]] @ Wcbf)[c],  q = k*NE + e.
// R4 skeleton (1 edge/wave, no pipelining, minimal VGPR, exit) but ALL random
// accesses on the deep vector-memory queue:
//   abd : 1 vector load, lane c -> slot c&15 (16 lines, dup x4)
//   intm: 1 per-lane dependent gather intm[tvv] -> readlane -> 16 SGPRs
//   cbf : te parked in 64B wave-private LDS; lane c loads row te[c>>2],
//         floats (c&3)*4.. -> ONE dwordx4 instr covers all 16 rows -> LDS ->
//         uniform broadcast reads (conflict-free)
//   sph : 42 lanes x dwordx4 -> LDS -> uniform reads
//   x_down: 16 coalesced 128B row gathers via SGPR bases
__global__ __launch_bounds__(256) void kS(
    const float* __restrict__ cbf, const float* __restrict__ sph,
    const int* __restrict__ abd, const int* __restrict__ intm,
    const unsigned short* __restrict__ x_down, const float* __restrict__ Wcbf,
    unsigned short* __restrict__ sumk) {
  __shared__ float cbf_lds[4][16][16];   // 4KB
  __shared__ int   te_lds[4][16];        // 256B
  __shared__ float sph_lds[4][172];      // ~2.7KB
  const int tid = threadIdx.x;
  const int w = tid >> 6, c = tid & 63;
  const int e = blockIdx.x * 4 + w;      // 20000 blocks * 4 waves

  // L0: abd (vector; 16 lines, dup x4 within line)
  const int tvv = abd[(size_t)(c & 15) * NEDGES + e];

  // sph park (independent; overlaps with index chain)
  if (c < 42)
    *reinterpret_cast<f32x4*>(&sph_lds[w][c * 4]) =
        *reinterpret_cast<const f32x4*>(sph + (size_t)e * 168 + c * 4);

  // L1: intm per-lane dependent gather (16 unique addrs, dup x4)
  const int ivv = intm[tvv];

  // park te for cbf addressing
  if (c < 16) te_lds[w][c] = tvv;

  // Wcbf column c (L2-resident after first blocks)
  float wc[16];
#pragma unroll
  for (int r = 0; r < 16; ++r) wc[r] = Wcbf[r * 64 + c];

  // es -> SGPRs (zero VGPR cost downstream)
  int es[16];
#pragma unroll
  for (int k = 0; k < 16; ++k) es[k] = __builtin_amdgcn_readlane(ivv, k);

  // L2a: cbf — one dwordx4 per lane covers all 16 rows
  const int tq = te_lds[w][c >> 2];
  const f32x4 cq = *reinterpret_cast<const f32x4*>(cbf + (size_t)tq * 16 + (c & 3) * 4);

  // L2b: x_down — 16 coalesced 128B row gathers
  unsigned short xr[16];
#pragma unroll
  for (int k = 0; k < 16; ++k) xr[k] = x_down[(size_t)es[k] * 64 + c];

  // park cbf tile (linear 16B/lane)
  *reinterpret_cast<f32x4*>(&cbf_lds[w][c >> 2][(c & 3) * 4]) = cq;

  // ---- compute ----
  float sk[7] = {0.f, 0.f, 0.f, 0.f, 0.f, 0.f, 0.f};
#pragma unroll
  for (int k = 0; k < 16; ++k) {
    const f32x4* cr = reinterpret_cast<const f32x4*>(&cbf_lds[w][k][0]);
    const f32x4 q0 = cr[0], q1 = cr[1], q2 = cr[2], q3 = cr[3];  // broadcast
    float proj = 0.f;
#pragma unroll
    for (int r = 0; r < 4; ++r) {
      proj = fmaf(q0[r], wc[r], proj);
      proj = fmaf(q1[r], wc[4 + r], proj);
      proj = fmaf(q2[r], wc[8 + r], proj);
      proj = fmaf(q3[r], wc[12 + r], proj);
    }
    const float row = bf2f((short)xr[k]) * proj;
#pragma unroll
    for (int s = 0; s < 7; ++s) sk[s] = fmaf(sph_lds[w][k * 7 + s], row, sk[s]);
  }
  short8 sv;
#pragma unroll
  for (int s = 0; s < 7; ++s) sv[s] = (short)f2bf(sk[s]);
  sv[7] = 0;
  *reinterpret_cast<short8*>(sumk + (size_t)e * 512 + c * 8) = sv;  // 1KB coalesced
}

// ---------------- kernel B2 (dense): sumk -> t -> bilinear MFMA -> up-proj -----
__global__ __launch_bounds__(256) void kB2(
    const float* __restrict__ sbfW1, const unsigned short* __restrict__ sumk,
    const unsigned short* __restrict__ WbilP, const unsigned short* __restrict__ WupcaP,
    const unsigned short* __restrict__ WupacP, float* __restrict__ out) {
  __shared__ unsigned short sk_lds[4][16][520];
  __shared__ unsigned short x_lds[4][16][72];
  const int tid = threadIdx.x;
  const int w = tid >> 6, l = tid & 63;
  const int el = l & 15, g = l >> 4;
  const int ebase = blockIdx.x * 64 + w * 16;

#pragma unroll
  for (int i = 0; i < 16; ++i) {
    const short8 v = *reinterpret_cast<const short8*>(sumk + (size_t)(ebase + i) * 512 + l * 8);
    *reinterpret_cast<short8*>(&sk_lds[w][i][l * 8]) = v;
  }

  float w1r[56];
  {
    const f32x4* wp = reinterpret_cast<const f32x4*>(sbfW1 + (size_t)(ebase + el) * 224 + g * 56);
#pragma unroll
    for (int qq = 0; qq < 14; ++qq) {
      f32x4 v = wp[qq];
      w1r[qq * 4 + 0] = v[0]; w1r[qq * 4 + 1] = v[1];
      w1r[qq * 4 + 2] = v[2]; w1r[qq * 4 + 3] = v[3];
    }
  }
  __syncthreads();

  const f32x4 z = {0.f, 0.f, 0.f, 0.f};
  f32x4 acc[4];
#pragma unroll
  for (int nt = 0; nt < 4; ++nt) acc[nt] = z;

#pragma unroll 4
  for (int kb = 0; kb < 64; ++kb) {
    const short8 skv = *reinterpret_cast<const short8*>(&sk_lds[w][el][kb * 8]);
    float skf[7];
#pragma unroll
    for (int s = 0; s < 7; ++s) skf[s] = bf2f(skv[s]);
    short8 a;
#pragma unroll
    for (int j = 0; j < 8; ++j) {
      float t = 0.f;
#pragma unroll
      for (int s = 0; s < 7; ++s) t = fmaf(w1r[j * 7 + s], skf[s], t);
      a[j] = (short)f2bf(t);
    }
    const unsigned short* bp = WbilP + (((kb * 4) * 64 + l) << 3);
#pragma unroll
    for (int nt = 0; nt < 4; ++nt) {
      short8 b = *reinterpret_cast<const short8*>(bp + ((nt * 64) << 3));
      acc[nt] = __builtin_amdgcn_mfma_f32_16x16x32_bf16(a, b, acc[nt], 0, 0, 0);
    }
  }

#pragma unroll
  for (int nt = 0; nt < 4; ++nt)
#pragma unroll
    for (int r = 0; r < 4; ++r)
      x_lds[w][g * 4 + r][nt * 16 + el] = f2bf(acc[nt][r]);
  __syncthreads();

  f32x4 aca[8], acb[8];
#pragma unroll
  for (int nt = 0; nt < 8; ++nt) { aca[nt] = z; acb[nt] = z; }
#pragma unroll
  for (int kb = 0; kb < 2; ++kb) {
    short8 a = *reinterpret_cast<const short8*>(&x_lds[w][el][kb * 32 + g * 8]);
#pragma unroll
    for (int nt = 0; nt < 8; ++nt) {
      short8 b1 = *reinterpret_cast<const short8*>(WupcaP + (((kb * 8 + nt) * 64 + l) << 3));
      short8 b2 = *reinterpret_cast<const short8*>(WupacP + (((kb * 8 + nt) * 64 + l) << 3));
      aca[nt] = __builtin_amdgcn_mfma_f32_16x16x32_bf16(a, b1, aca[nt], 0, 0, 0);
      acb[nt] = __builtin_amdgcn_mfma_f32_16x16x32_bf16(a, b2, acb[nt], 0, 0, 0);
    }
  }
  const float inv = 0.70710678118654752f;
#pragma unroll
  for (int nt = 0; nt < 8; ++nt)
#pragma unroll
    for (int r = 0; r < 4; ++r) {
      float v = (sSiLU(aca[nt][r]) + sSiLU(acb[nt][r ^ 1])) * inv;
      out[(size_t)(ebase + g * 4 + r) * 128 + nt * 16 + el] = v;
    }
}

// ---------------- kernel B (fallback, round-2 structure; bf16 x_down) ----------
__global__ __launch_bounds__(256) void kBfb(
    const float* __restrict__ cbf, const float* __restrict__ sbfW1,
    const float* __restrict__ sph, const int* __restrict__ abd,
    const int* __restrict__ intm, const unsigned short* __restrict__ x_down,
    const unsigned short* __restrict__ WbilP, const unsigned short* __restrict__ WupcaP,
    const unsigned short* __restrict__ WupacP, const float* __restrict__ Wcbf,
    float* __restrict__ out) {
  __shared__ unsigned short sumk[4][16][520];
  __shared__ unsigned short x_lds[4][16][72];
  const int tid = threadIdx.x;
  const int w = tid >> 6, l = tid & 63;
  const int el = l & 15, g = l >> 4;
  const int ebase = blockIdx.x * 64 + w * 16;
  const int c = l;

  float wc[16];
#pragma unroll
  for (int r = 0; r < 16; ++r) wc[r] = Wcbf[r * 64 + c];

  int te[16], es[16];
#pragma unroll
  for (int k = 0; k < 16; ++k)
    te[k] = __builtin_amdgcn_readfirstlane(abd[k * NEDGES + ebase]);
#pragma unroll
  for (int k = 0; k < 16; ++k)
    es[k] = __builtin_amdgcn_readfirstlane(intm[te[k]]);

  for (int ee = 0; ee < 16; ++ee) {
    const int e = ebase + ee;
    const int en = (ee < 15) ? (e + 1) : e;
    int te2[16], es2[16];
#pragma unroll
    for (int k = 0; k < 16; ++k)
      te2[k] = __builtin_amdgcn_readfirstlane(abd[k * NEDGES + en]);
    float xr[16];
#pragma unroll
    for (int k = 0; k < 16; ++k)
      xr[k] = bf2f((short)x_down[(size_t)es[k] * 64 + c]);
#pragma unroll
    for (int k = 0; k < 16; ++k)
      es2[k] = __builtin_amdgcn_readfirstlane(intm[te2[k]]);

    const float* spe = sph + (size_t)e * 168;
    float sk[7] = {0.f, 0.f, 0.f, 0.f, 0.f, 0.f, 0.f};
#pragma unroll
    for (int k = 0; k < 16; ++k) {
      const f32x4* cp = reinterpret_cast<const f32x4*>(cbf + (size_t)te[k] * 16);
      const f32x4 c0 = cp[0], c1 = cp[1], c2 = cp[2], c3 = cp[3];
      float proj = 0.f;
#pragma unroll
      for (int r = 0; r < 4; ++r) {
        proj = fmaf(c0[r], wc[r], proj);
        proj = fmaf(c1[r], wc[4 + r], proj);
        proj = fmaf(c2[r], wc[8 + r], proj);
        proj = fmaf(c3[r], wc[12 + r], proj);
      }
      const float row = xr[k] * proj;
#pragma unroll
      for (int s = 0; s < 7; ++s) sk[s] = fmaf(spe[k * 7 + s], row, sk[s]);
    }
    short8 sv;
#pragma unroll
    for (int s = 0; s < 7; ++s) sv[s] = (short)f2bf(sk[s]);
    sv[7] = 0;
    *reinterpret_cast<short8*>(&sumk[w][ee][c * 8]) = sv;
#pragma unroll
    for (int k = 0; k < 16; ++k) { te[k] = te2[k]; es[k] = es2[k]; }
  }
  __syncthreads();

  float w1r[56];
  {
    const f32x4* wp = reinterpret_cast<const f32x4*>(sbfW1 + (size_t)(ebase + el) * 224 + g * 56);
#pragma unroll
    for (int qq = 0; qq < 14; ++qq) {
      f32x4 v = wp[qq];
      w1r[qq * 4 + 0] = v[0]; w1r[qq * 4 + 1] = v[1];
      w1r[qq * 4 + 2] = v[2]; w1r[qq * 4 + 3] = v[3];
    }
  }
  const f32x4 z = {0.f, 0.f, 0.f, 0.f};
  f32x4 acc[4];
#pragma unroll
  for (int nt = 0; nt < 4; ++nt) acc[nt] = z;
#pragma unroll 4
  for (int kb = 0; kb < 64; ++kb) {
    const short8 skv = *reinterpret_cast<const short8*>(&sumk[w][el][kb * 8]);
    float skf[7];
#pragma unroll
    for (int s = 0; s < 7; ++s) skf[s] = bf2f(skv[s]);
    short8 a;
#pragma unroll
    for (int j = 0; j < 8; ++j) {
      float t = 0.f;
#pragma unroll
      for (int s = 0; s < 7; ++s) t = fmaf(w1r[j * 7 + s], skf[s], t);
      a[j] = (short)f2bf(t);
    }
    const unsigned short* bp = WbilP + (((kb * 4) * 64 + l) << 3);
#pragma unroll
    for (int nt = 0; nt < 4; ++nt) {
      short8 b = *reinterpret_cast<const short8*>(bp + ((nt * 64) << 3));
      acc[nt] = __builtin_amdgcn_mfma_f32_16x16x32_bf16(a, b, acc[nt], 0, 0, 0);
    }
  }
#pragma unroll
  for (int nt = 0; nt < 4; ++nt)
#pragma unroll
    for (int r = 0; r < 4; ++r)
      x_lds[w][g * 4 + r][nt * 16 + el] = f2bf(acc[nt][r]);
  __syncthreads();

  f32x4 aca[8], acb[8];
#pragma unroll
  for (int nt = 0; nt < 8; ++nt) { aca[nt] = z; acb[nt] = z; }
#pragma unroll
  for (int kb = 0; kb < 2; ++kb) {
    short8 a = *reinterpret_cast<const short8*>(&x_lds[w][el][kb * 32 + g * 8]);
#pragma unroll
    for (int nt = 0; nt < 8; ++nt) {
      short8 b1 = *reinterpret_cast<const short8*>(WupcaP + (((kb * 8 + nt) * 64 + l) << 3));
      short8 b2 = *reinterpret_cast<const short8*>(WupacP + (((kb * 8 + nt) * 64 + l) << 3));
      aca[nt] = __builtin_amdgcn_mfma_f32_16x16x32_bf16(a, b1, aca[nt], 0, 0, 0);
      acb[nt] = __builtin_amdgcn_mfma_f32_16x16x32_bf16(a, b2, acb[nt], 0, 0, 0);
    }
  }
  const float inv = 0.70710678118654752f;
#pragma unroll
  for (int nt = 0; nt < 8; ++nt)
#pragma unroll
    for (int r = 0; r < 4; ++r) {
      float v = (sSiLU(aca[nt][r]) + sSiLU(acb[nt][r ^ 1])) * inv;
      out[(size_t)(ebase + g * 4 + r) * 128 + nt * 16 + el] = v;
    }
}

// ---------------- launch ----------------
extern "C" void kernel_launch(void* const* d_in, const int* in_sizes, int n_in,
                              void* d_out, int out_size, void* d_ws, size_t ws_size,
                              hipStream_t stream) {
  const float* m     = (const float*)d_in[0];
  const float* rbf   = (const float*)d_in[1];
  const float* cbf   = (const float*)d_in[2];
  const float* sbfW1 = (const float*)d_in[3];
  const float* sph   = (const float*)d_in[4];
  const int* intm = (const int*)d_in[8];
  const int* abd  = (const int*)d_in[9];
  const float* Wd    = (const float*)d_in[10];
  const float* Wrbf  = (const float*)d_in[11];
  const float* Wcbf  = (const float*)d_in[12];
  const float* Wdown = (const float*)d_in[13];
  const float* Wbil  = (const float*)d_in[14];
  const float* Wupca = (const float*)d_in[15];
  const float* Wupac = (const float*)d_in[16];

  char* ws = (char*)d_ws;
  unsigned short* WdP    = (unsigned short*)(ws + 0);
  unsigned short* WrbfP  = (unsigned short*)(ws + 32768);
  unsigned short* WdownP = (unsigned short*)(ws + 40960);
  unsigned short* WbilP  = (unsigned short*)(ws + 57344);
  unsigned short* WupcaP = (unsigned short*)(ws + 319488);
  unsigned short* WupacP = (unsigned short*)(ws + 335872);
  unsigned short* x_down = (unsigned short*)(ws + 352256);            // 10,240,000 B
  unsigned short* sumk   = (unsigned short*)(ws + 352256 + 10240000); // 81,920,000 B
  const size_t needed = 352256ull + 10240000ull + 81920000ull;

  kpack<<<688, 256, 0, stream>>>(Wd, Wrbf, Wdown, Wbil, Wupca, Wupac,
                                 WdP, WrbfP, WdownP, WbilP, WupcaP, WupacP);
  kA<<<1250, 256, 0, stream>>>(m, rbf, WdP, WrbfP, WdownP, x_down);
  if (ws_size >= needed) {
    kS<<<20000, 256, 0, stream>>>(cbf, sph, abd, intm, x_down, Wcbf, sumk);
    kB2<<<1250, 256, 0, stream>>>(sbfW1, sumk, WbilP, WupcaP, WupacP, (float*)d_out);
  } else {
    kBfb<<<1250, 256, 0, stream>>>(cbf, sbfW1, sph, abd, intm, x_down,
                                   WbilP, WupcaP, WupacP, Wcbf, (float*)d_out);
  }
}

// Round 8
// 265.488 us; speedup vs baseline: 2.0048x; 1.1589x over previous
//
#include <hip/hip_runtime.h>
#include <hip/hip_bf16.h>

#define NEDGES 80000
#define NTRIP  640000
#define NQUAD  1280000

typedef __attribute__((ext_vector_type(8))) short short8;
typedef __attribute__((ext_vector_type(4))) float f32x4;

__device__ __forceinline__ unsigned short f2bf(float f) {
  __hip_bfloat16 h = __float2bfloat16(f);
  return reinterpret_cast<unsigned short&>(h);
}
__device__ __forceinline__ float bf2f(short s) {
  union { unsigned u; float f; } u;
  u.u = ((unsigned)(unsigned short)s) << 16;
  return u.f;
}
__device__ __forceinline__ float sSiLU(float x) {
  return x * (1.0f / 0.6f) / (1.0f + __expf(-x));
}

// ---------------- pack kernel: weights -> bf16, MFMA B-fragment order ----------
__device__ __forceinline__ void pack_one(const float* __restrict__ W,
                                         unsigned short* __restrict__ dst,
                                         int p, int NT, int Ksrc, int N) {
  int j = p & 7;
  int l = (p >> 3) & 63;
  int rest = p >> 9;
  int nt = rest % NT;
  int kb = rest / NT;
  int k = kb * 32 + ((l >> 4) << 3) + j;
  int n = nt * 16 + (l & 15);
  float v = (k < Ksrc) ? W[(size_t)k * N + n] : 0.0f;
  dst[p] = f2bf(v);
}

__global__ __launch_bounds__(256) void kpack(
    const float* __restrict__ Wd, const float* __restrict__ Wrbf,
    const float* __restrict__ Wdown, const float* __restrict__ Wbil,
    const float* __restrict__ Wupca, const float* __restrict__ Wupac,
    unsigned short* __restrict__ WdP, unsigned short* __restrict__ WrbfP,
    unsigned short* __restrict__ WdownP, unsigned short* __restrict__ WbilP,
    unsigned short* __restrict__ WupcaP, unsigned short* __restrict__ WupacP) {
  int idx = blockIdx.x * 256 + threadIdx.x;
  if (idx < 16384)        pack_one(Wd,    WdP,    idx,          8, 128,  128);
  else if (idx < 20480)   pack_one(Wrbf,  WrbfP,  idx - 16384,  8, 16,   128);
  else if (idx < 28672)   pack_one(Wdown, WdownP, idx - 20480,  4, 128,  64);
  else if (idx < 159744)  pack_one(Wbil,  WbilP,  idx - 28672,  4, 2048, 64);
  else if (idx < 167936)  pack_one(Wupca, WupcaP, idx - 159744, 8, 64,   128);
  else if (idx < 176128)  pack_one(Wupac, WupacP, idx - 167936, 8, 64,   128);
}

// ---------------- kernel A: x_down(bf16) = ss( (ss(m@Wd)*(rbf@Wrbf)) @ Wdown ) --
__global__ __launch_bounds__(256) void kA(
    const float* __restrict__ m, const float* __restrict__ rbf,
    const unsigned short* __restrict__ WdP, const unsigned short* __restrict__ WrbfP,
    const unsigned short* __restrict__ WdownP, unsigned short* __restrict__ x_down) {
  __shared__ unsigned short h_lds[4][16][136];
  const int tid = threadIdx.x;
  const int w = tid >> 6, l = tid & 63;
  const int el = l & 15, g = l >> 4;
  const int ebase = blockIdx.x * 64 + w * 16;

  short8 am[4];
  {
    const float* mrow = m + (size_t)(ebase + el) * 128 + g * 8;
#pragma unroll
    for (int kb = 0; kb < 4; ++kb) {
      const f32x4 lo = *reinterpret_cast<const f32x4*>(mrow + kb * 32);
      const f32x4 hi = *reinterpret_cast<const f32x4*>(mrow + kb * 32 + 4);
      short8 a;
      a[0] = f2bf(lo[0]); a[1] = f2bf(lo[1]); a[2] = f2bf(lo[2]); a[3] = f2bf(lo[3]);
      a[4] = f2bf(hi[0]); a[5] = f2bf(hi[1]); a[6] = f2bf(hi[2]); a[7] = f2bf(hi[3]);
      am[kb] = a;
    }
  }
  short8 ar;
  {
    const float* rrow = rbf + (size_t)(ebase + el) * 16 + (g & 1) * 8;
    const f32x4 lo = *reinterpret_cast<const f32x4*>(rrow);
    const f32x4 hi = *reinterpret_cast<const f32x4*>(rrow + 4);
    ar[0] = f2bf(lo[0]); ar[1] = f2bf(lo[1]); ar[2] = f2bf(lo[2]); ar[3] = f2bf(lo[3]);
    ar[4] = f2bf(hi[0]); ar[5] = f2bf(hi[1]); ar[6] = f2bf(hi[2]); ar[7] = f2bf(hi[3]);
  }

  f32x4 acc1[8], acc2[8];
  const f32x4 z = {0.f, 0.f, 0.f, 0.f};
#pragma unroll
  for (int nt = 0; nt < 8; ++nt) { acc1[nt] = z; acc2[nt] = z; }

#pragma unroll
  for (int kb = 0; kb < 4; ++kb) {
#pragma unroll
    for (int nt = 0; nt < 8; ++nt) {
      short8 b = *reinterpret_cast<const short8*>(WdP + (((kb * 8 + nt) * 64 + l) << 3));
      acc1[nt] = __builtin_amdgcn_mfma_f32_16x16x32_bf16(am[kb], b, acc1[nt], 0, 0, 0);
    }
  }
#pragma unroll
  for (int nt = 0; nt < 8; ++nt) {
    short8 b = *reinterpret_cast<const short8*>(WrbfP + ((nt * 64 + l) << 3));
    acc2[nt] = __builtin_amdgcn_mfma_f32_16x16x32_bf16(ar, b, acc2[nt], 0, 0, 0);
  }

#pragma unroll
  for (int nt = 0; nt < 8; ++nt)
#pragma unroll
    for (int r = 0; r < 4; ++r) {
      float h = sSiLU(acc1[nt][r]) * acc2[nt][r];
      h_lds[w][g * 4 + r][nt * 16 + el] = f2bf(h);
    }
  __syncthreads();

  f32x4 acc3[4];
#pragma unroll
  for (int nt = 0; nt < 4; ++nt) acc3[nt] = z;
#pragma unroll
  for (int kb = 0; kb < 4; ++kb) {
    short8 a = *reinterpret_cast<const short8*>(&h_lds[w][el][kb * 32 + g * 8]);
#pragma unroll
    for (int nt = 0; nt < 4; ++nt) {
      short8 b = *reinterpret_cast<const short8*>(WdownP + (((kb * 4 + nt) * 64 + l) << 3));
      acc3[nt] = __builtin_amdgcn_mfma_f32_16x16x32_bf16(a, b, acc3[nt], 0, 0, 0);
    }
  }
#pragma unroll
  for (int nt = 0; nt < 4; ++nt)
#pragma unroll
    for (int r = 0; r < 4; ++r)
      x_down[(size_t)(ebase + g * 4 + r) * 64 + nt * 16 + el] = f2bf(sSiLU(acc3[nt][r]));
}

// ---------------- kernel G: y[t][c] = x_down[intm[t]][c] * (cbf[t] @ Wcbf)[c] ---
// Dense per-triplet: intm coalesced, cbf sequential (1KB/group), x_down gathers
// hit a 10MB L2/L3-resident table, y write coalesced. 16 triplets per wave-iter
// (cbf parked in wave-private LDS via one dwordx4/lane), 4 iters per wave.
__global__ __launch_bounds__(256) void kG(
    const float* __restrict__ cbf, const int* __restrict__ intm,
    const unsigned short* __restrict__ x_down, const float* __restrict__ Wcbf,
    unsigned short* __restrict__ y) {
  __shared__ float cbf_lds[4][16][16];   // 4KB, wave-private slices
  const int tid = threadIdx.x;
  const int w = tid >> 6, c = tid & 63;
  const int wid = blockIdx.x * 4 + w;    // 10000 waves

  float wc[16];
#pragma unroll
  for (int r = 0; r < 16; ++r) wc[r] = Wcbf[r * 64 + c];

#pragma unroll
  for (int it = 0; it < 4; ++it) {
    const int t0 = (wid * 4 + it) * 16;  // 16 consecutive triplets

    const int ivv = intm[t0 + (c & 15)];                       // coalesced, dup x4
    const f32x4 cq = *reinterpret_cast<const f32x4*>(          // 1KB contiguous
        cbf + (size_t)(t0 + (c >> 2)) * 16 + (c & 3) * 4);
    *reinterpret_cast<f32x4*>(&cbf_lds[w][c >> 2][(c & 3) * 4]) = cq;

    int es[16];
#pragma unroll
    for (int k = 0; k < 16; ++k) es[k] = __builtin_amdgcn_readlane(ivv, k);

    unsigned short xr[16];
#pragma unroll
    for (int k = 0; k < 16; ++k) xr[k] = x_down[(size_t)es[k] * 64 + c];

#pragma unroll
    for (int j = 0; j < 16; ++j) {
      const f32x4* cr = reinterpret_cast<const f32x4*>(&cbf_lds[w][j][0]);
      const f32x4 q0 = cr[0], q1 = cr[1], q2 = cr[2], q3 = cr[3];  // broadcast
      float proj = 0.f;
#pragma unroll
      for (int r = 0; r < 4; ++r) {
        proj = fmaf(q0[r], wc[r], proj);
        proj = fmaf(q1[r], wc[4 + r], proj);
        proj = fmaf(q2[r], wc[8 + r], proj);
        proj = fmaf(q3[r], wc[12 + r], proj);
      }
      y[(size_t)(t0 + j) * 64 + c] = f2bf(bf2f((short)xr[j]) * proj);
    }
  }
}

// ---------------- kernel S2: sumk[e][c][s] = sum_k sph[e][k][s] * y[abd[k,e]][c]
// Single indirection (abd -> y row), minimal VGPR, 8 edges per wave grid-stride
// (waves stay resident; TLP hides the gather latency).
__global__ __launch_bounds__(256) void kS2(
    const float* __restrict__ sph, const int* __restrict__ abd,
    const unsigned short* __restrict__ y, unsigned short* __restrict__ sumk) {
  __shared__ float sph_lds[4][172];
  const int tid = threadIdx.x;
  const int w = tid >> 6, c = tid & 63;
  const int wid = blockIdx.x * 4 + w;    // 10000 waves

#pragma unroll
  for (int it = 0; it < 8; ++it) {
    const int e = wid * 8 + it;

    const int tvv = abd[(size_t)(c & 15) * NEDGES + e];   // 16 lines, dup x4
    if (c < 42)
      *reinterpret_cast<f32x4*>(&sph_lds[w][c * 4]) =
          *reinterpret_cast<const f32x4*>(sph + (size_t)e * 168 + c * 4);

    int te[16];
#pragma unroll
    for (int k = 0; k < 16; ++k) te[k] = __builtin_amdgcn_readlane(tvv, k);

    unsigned short yv[16];
#pragma unroll
    for (int k = 0; k < 16; ++k) yv[k] = y[(size_t)te[k] * 64 + c];  // 128B rows

    float sk[7] = {0.f, 0.f, 0.f, 0.f, 0.f, 0.f, 0.f};
#pragma unroll
    for (int k = 0; k < 16; ++k) {
      const float row = bf2f((short)yv[k]);
#pragma unroll
      for (int s = 0; s < 7; ++s) sk[s] = fmaf(sph_lds[w][k * 7 + s], row, sk[s]);
    }
    short8 sv;
#pragma unroll
    for (int s = 0; s < 7; ++s) sv[s] = (short)f2bf(sk[s]);
    sv[7] = 0;
    *reinterpret_cast<short8*>(sumk + (size_t)e * 512 + c * 8) = sv;  // 1KB coalesced
  }
}

// ---------------- kernel S (R7 fused fallback: used if workspace is small) ----
__global__ __launch_bounds__(256) void kS(
    const float* __restrict__ cbf, const float* __restrict__ sph,
    const int* __restrict__ abd, const int* __restrict__ intm,
    const unsigned short* __restrict__ x_down, const float* __restrict__ Wcbf,
    unsigned short* __restrict__ sumk) {
  __shared__ float cbf_lds[4][16][16];
  __shared__ int   te_lds[4][16];
  __shared__ float sph_lds[4][172];
  const int tid = threadIdx.x;
  const int w = tid >> 6, c = tid & 63;
  const int e = blockIdx.x * 4 + w;

  const int tvv = abd[(size_t)(c & 15) * NEDGES + e];
  if (c < 42)
    *reinterpret_cast<f32x4*>(&sph_lds[w][c * 4]) =
        *reinterpret_cast<const f32x4*>(sph + (size_t)e * 168 + c * 4);
  const int ivv = intm[tvv];
  if (c < 16) te_lds[w][c] = tvv;

  float wc[16];
#pragma unroll
  for (int r = 0; r < 16; ++r) wc[r] = Wcbf[r * 64 + c];

  int es[16];
#pragma unroll
  for (int k = 0; k < 16; ++k) es[k] = __builtin_amdgcn_readlane(ivv, k);

  const int tq = te_lds[w][c >> 2];
  const f32x4 cq = *reinterpret_cast<const f32x4*>(cbf + (size_t)tq * 16 + (c & 3) * 4);

  unsigned short xr[16];
#pragma unroll
  for (int k = 0; k < 16; ++k) xr[k] = x_down[(size_t)es[k] * 64 + c];

  *reinterpret_cast<f32x4*>(&cbf_lds[w][c >> 2][(c & 3) * 4]) = cq;

  float sk[7] = {0.f, 0.f, 0.f, 0.f, 0.f, 0.f, 0.f};
#pragma unroll
  for (int k = 0; k < 16; ++k) {
    const f32x4* cr = reinterpret_cast<const f32x4*>(&cbf_lds[w][k][0]);
    const f32x4 q0 = cr[0], q1 = cr[1], q2 = cr[2], q3 = cr[3];
    float proj = 0.f;
#pragma unroll
    for (int r = 0; r < 4; ++r) {
      proj = fmaf(q0[r], wc[r], proj);
      proj = fmaf(q1[r], wc[4 + r], proj);
      proj = fmaf(q2[r], wc[8 + r], proj);
      proj = fmaf(q3[r], wc[12 + r], proj);
    }
    const float row = bf2f((short)xr[k]) * proj;
#pragma unroll
    for (int s = 0; s < 7; ++s) sk[s] = fmaf(sph_lds[w][k * 7 + s], row, sk[s]);
  }
  short8 sv;
#pragma unroll
  for (int s = 0; s < 7; ++s) sv[s] = (short)f2bf(sk[s]);
  sv[7] = 0;
  *reinterpret_cast<short8*>(sumk + (size_t)e * 512 + c * 8) = sv;
}

// ---------------- kernel B2 (dense): sumk -> t -> bilinear MFMA -> up-proj -----
__global__ __launch_bounds__(256) void kB2(
    const float* __restrict__ sbfW1, const unsigned short* __restrict__ sumk,
    const unsigned short* __restrict__ WbilP, const unsigned short* __restrict__ WupcaP,
    const unsigned short* __restrict__ WupacP, float* __restrict__ out) {
  __shared__ unsigned short sk_lds[4][16][520];
  __shared__ unsigned short x_lds[4][16][72];
  const int tid = threadIdx.x;
  const int w = tid >> 6, l = tid & 63;
  const int el = l & 15, g = l >> 4;
  const int ebase = blockIdx.x * 64 + w * 16;

#pragma unroll
  for (int i = 0; i < 16; ++i) {
    const short8 v = *reinterpret_cast<const short8*>(sumk + (size_t)(ebase + i) * 512 + l * 8);
    *reinterpret_cast<short8*>(&sk_lds[w][i][l * 8]) = v;
  }

  float w1r[56];
  {
    const f32x4* wp = reinterpret_cast<const f32x4*>(sbfW1 + (size_t)(ebase + el) * 224 + g * 56);
#pragma unroll
    for (int qq = 0; qq < 14; ++qq) {
      f32x4 v = wp[qq];
      w1r[qq * 4 + 0] = v[0]; w1r[qq * 4 + 1] = v[1];
      w1r[qq * 4 + 2] = v[2]; w1r[qq * 4 + 3] = v[3];
    }
  }
  __syncthreads();

  const f32x4 z = {0.f, 0.f, 0.f, 0.f};
  f32x4 acc[4];
#pragma unroll
  for (int nt = 0; nt < 4; ++nt) acc[nt] = z;

#pragma unroll 4
  for (int kb = 0; kb < 64; ++kb) {
    const short8 skv = *reinterpret_cast<const short8*>(&sk_lds[w][el][kb * 8]);
    float skf[7];
#pragma unroll
    for (int s = 0; s < 7; ++s) skf[s] = bf2f(skv[s]);
    short8 a;
#pragma unroll
    for (int j = 0; j < 8; ++j) {
      float t = 0.f;
#pragma unroll
      for (int s = 0; s < 7; ++s) t = fmaf(w1r[j * 7 + s], skf[s], t);
      a[j] = (short)f2bf(t);
    }
    const unsigned short* bp = WbilP + (((kb * 4) * 64 + l) << 3);
#pragma unroll
    for (int nt = 0; nt < 4; ++nt) {
      short8 b = *reinterpret_cast<const short8*>(bp + ((nt * 64) << 3));
      acc[nt] = __builtin_amdgcn_mfma_f32_16x16x32_bf16(a, b, acc[nt], 0, 0, 0);
    }
  }

#pragma unroll
  for (int nt = 0; nt < 4; ++nt)
#pragma unroll
    for (int r = 0; r < 4; ++r)
      x_lds[w][g * 4 + r][nt * 16 + el] = f2bf(acc[nt][r]);
  __syncthreads();

  f32x4 aca[8], acb[8];
#pragma unroll
  for (int nt = 0; nt < 8; ++nt) { aca[nt] = z; acb[nt] = z; }
#pragma unroll
  for (int kb = 0; kb < 2; ++kb) {
    short8 a = *reinterpret_cast<const short8*>(&x_lds[w][el][kb * 32 + g * 8]);
#pragma unroll
    for (int nt = 0; nt < 8; ++nt) {
      short8 b1 = *reinterpret_cast<const short8*>(WupcaP + (((kb * 8 + nt) * 64 + l) << 3));
      short8 b2 = *reinterpret_cast<const short8*>(WupacP + (((kb * 8 + nt) * 64 + l) << 3));
      aca[nt] = __builtin_amdgcn_mfma_f32_16x16x32_bf16(a, b1, aca[nt], 0, 0, 0);
      acb[nt] = __builtin_amdgcn_mfma_f32_16x16x32_bf16(a, b2, acb[nt], 0, 0, 0);
    }
  }
  const float inv = 0.70710678118654752f;
#pragma unroll
  for (int nt = 0; nt < 8; ++nt)
#pragma unroll
    for (int r = 0; r < 4; ++r) {
      float v = (sSiLU(aca[nt][r]) + sSiLU(acb[nt][r ^ 1])) * inv;
      out[(size_t)(ebase + g * 4 + r) * 128 + nt * 16 + el] = v;
    }
}

// ---------------- launch ----------------
extern "C" void kernel_launch(void* const* d_in, const int* in_sizes, int n_in,
                              void* d_out, int out_size, void* d_ws, size_t ws_size,
                              hipStream_t stream) {
  const float* m     = (const float*)d_in[0];
  const float* rbf   = (const float*)d_in[1];
  const float* cbf   = (const float*)d_in[2];
  const float* sbfW1 = (const float*)d_in[3];
  const float* sph   = (const float*)d_in[4];
  const int* intm = (const int*)d_in[8];
  const int* abd  = (const int*)d_in[9];
  const float* Wd    = (const float*)d_in[10];
  const float* Wrbf  = (const float*)d_in[11];
  const float* Wcbf  = (const float*)d_in[12];
  const float* Wdown = (const float*)d_in[13];
  const float* Wbil  = (const float*)d_in[14];
  const float* Wupca = (const float*)d_in[15];
  const float* Wupac = (const float*)d_in[16];

  char* ws = (char*)d_ws;
  unsigned short* WdP    = (unsigned short*)(ws + 0);
  unsigned short* WrbfP  = (unsigned short*)(ws + 32768);
  unsigned short* WdownP = (unsigned short*)(ws + 40960);
  unsigned short* WbilP  = (unsigned short*)(ws + 57344);
  unsigned short* WupcaP = (unsigned short*)(ws + 319488);
  unsigned short* WupacP = (unsigned short*)(ws + 335872);
  unsigned short* x_down = (unsigned short*)(ws + 352256);             // 10,240,000 B
  unsigned short* y      = (unsigned short*)(ws + 352256 + 10240000);  // 81,920,000 B
  unsigned short* sumk2  = (unsigned short*)(ws + 352256 + 10240000 + 81920000); // 81,920,000 B
  unsigned short* sumk1  = y;  // fused path reuses y's slot for sumk
  const size_t needed_split = 352256ull + 10240000ull + 81920000ull + 81920000ull;
  const size_t needed_fused = 352256ull + 10240000ull + 81920000ull;

  kpack<<<688, 256, 0, stream>>>(Wd, Wrbf, Wdown, Wbil, Wupca, Wupac,
                                 WdP, WrbfP, WdownP, WbilP, WupcaP, WupacP);
  kA<<<1250, 256, 0, stream>>>(m, rbf, WdP, WrbfP, WdownP, x_down);
  if (ws_size >= needed_split) {
    kG<<<2500, 256, 0, stream>>>(cbf, intm, x_down, Wcbf, y);
    kS2<<<2500, 256, 0, stream>>>(sph, abd, y, sumk2);
    kB2<<<1250, 256, 0, stream>>>(sbfW1, sumk2, WbilP, WupcaP, WupacP, (float*)d_out);
  } else {
    kS<<<20000, 256, 0, stream>>>(cbf, sph, abd, intm, x_down, Wcbf, sumk1);
    kB2<<<1250, 256, 0, stream>>>(sbfW1, sumk1, WbilP, WupcaP, WupacP, (float*)d_out);
  }
}